// Round 8
// baseline (1039.391 us; speedup 1.0000x reference)
//
#include <hip/hip_runtime.h>
#include <hip/hip_bf16.h>
#include <math.h>

#define DEV __device__ __forceinline__

typedef __attribute__((ext_vector_type(4))) float f32x4;
typedef __attribute__((ext_vector_type(8))) __bf16 bf16x8;

// ---------------- problem constants ----------------
constexpr int N_CONST = 8192;
constexpr int E_CONST = 131072;

constexpr float SQ3F     = 1.7320508075688772f;
constexpr float INV_SQ3F = 0.57735026918962576f;
constexpr float FAN_TP   = 0.20412414523193150f;   // 24^-0.5
constexpr float FAN_TP_V = 0.35355339059327373f;   // sqrt(3)*24^-0.5
constexpr float FAN_DOT  = 0.11180339887498949f;   // 80^-0.5
constexpr float INV16SQ  = 0.25f;                  // 16^-0.5
constexpr float INV8SQ   = 0.35355339059327373f;   // 8^-0.5
constexpr float HID_SC   = 0.125f;                 // 64^-0.5

// ---------------- workspace layout (float offsets) ----------------
enum : int {
  OFF_LIN0 = 0,
  OFF_LIN1 = OFF_LIN0 + 256,
  OFF_HQ0  = OFF_LIN1 + 64,
  OFF_HQ1  = OFF_HQ0 + 256,
  OFF_FCK1 = OFF_HQ1 + 64,
  OFF_FCK2 = OFF_FCK1 + 2048,
  OFF_FCV1 = OFF_FCK2 + 36864,
  OFF_FCV2 = OFF_FCV1 + 2048,
  OFF_DOT0 = OFF_FCV2 + 73728,
  OFF_DOT1 = OFF_DOT0 + 128,
  OFF_RB0  = OFF_DOT1 + 32,
  OFF_RB1  = OFF_RB0 + 128,
  OFF_RE0  = OFF_RB1 + 32,
  OFF_RE1  = OFF_RE0 + 128,
  OFF_F    = OFF_RE1 + 32,
  OFF_POS  = OFF_F + N_CONST * 40,
  OFF_X    = OFF_POS + N_CONST * 3,
  OFF_Q    = OFF_X + N_CONST * 40,
  OFF_AGG  = OFF_Q + N_CONST * 20,
  OFF_LOGIT= OFF_AGG + N_CONST * 40,
  OFF_CUT  = OFF_LOGIT + E_CONST,
  OFF_WGT  = OFF_CUT + E_CONST,
  OFF_FLAG = OFF_WGT + E_CONST,     // int flag in a float slot
  OFF_WT   = (OFF_FLAG + 7) & ~3,   // bf16 WtV [2][576][64]
  OFF_WTK  = OFF_WT + 36864,        // bf16 WtK [2][288][64]
  OFF_COL  = OFF_WTK + 18432,       // CSR edge list (E ints)
  OFF_ROWP = OFF_COL + E_CONST,     // rowptr (N+1 ints)
  OFF_DEG  = OFF_ROWP + N_CONST + 1,
  OFF_CNT  = OFF_DEG + N_CONST,
  OFF_VAL  = OFF_CNT + N_CONST,     // bf16 val [E][40] (E*20 f32 slots)
};

// ---------------- dtype detection ----------------
__global__ void k_detect(const unsigned int* __restrict__ words, int* __restrict__ flag) {
  if (blockIdx.x != 0 || threadIdx.x != 0) return;
  int cnt = 0;
  for (int i = 0; i < 512; ++i) {
    unsigned b = (words[i] >> 8) & 0x7Fu;
    cnt += (b >= 0x3Au && b <= 0x43u) ? 1 : 0;
  }
  *flag = (cnt > 256) ? 1 : 0;
}

// ---------------- convert all float inputs to f32 in ws ----------------
struct CvtArgs {
  const void* src[16];
  int n[16];
  int off[16];
};

template <bool BF>
__global__ void k_cvt(CvtArgs a, float* __restrict__ ws, const int* __restrict__ flag) {
  if ((*flag != 0) != BF) return;
  int tid = blockIdx.x * blockDim.x + threadIdx.x;
  int stride = gridDim.x * blockDim.x;
  for (int arr = 0; arr < 16; ++arr) {
    float* dst = ws + a.off[arr];
    int n = a.n[arr];
    if (BF) {
      const __hip_bfloat16* s = (const __hip_bfloat16*)a.src[arr];
      for (int i = tid; i < n; i += stride) dst[i] = __bfloat162float(s[i]);
    } else {
      const float* s = (const float*)a.src[arr];
      for (int i = tid; i < n; i += stride) dst[i] = s[i];
    }
  }
}

// ---------------- helpers ----------------
DEV unsigned short f2bf(float f) {   // RNE f32 -> bf16 bits
  unsigned int u = __float_as_uint(f);
  u = u + 0x7FFFu + ((u >> 16) & 1u);
  return (unsigned short)(u >> 16);
}

template <int MO0, int MO1>
DEV void lin_apply(const float* __restrict__ in40, const float* __restrict__ W0,
                   const float* __restrict__ W1, float* __restrict__ out) {
#pragma unroll
  for (int j = 0; j < MO0; ++j) {
    float a = 0.f;
#pragma unroll
    for (int i = 0; i < 16; ++i) a += in40[i] * W0[i * MO0 + j];
    out[j] = a * INV16SQ;
  }
#pragma unroll
  for (int w = 0; w < MO1; ++w) {
    float a0 = 0.f, a1 = 0.f, a2 = 0.f;
#pragma unroll
    for (int u = 0; u < 8; ++u) {
      float wt = W1[u * MO1 + w];
      a0 += in40[16 + u * 3 + 0] * wt;
      a1 += in40[16 + u * 3 + 1] * wt;
      a2 += in40[16 + u * 3 + 2] * wt;
    }
    out[MO0 + w * 3 + 0] = a0 * INV8SQ;
    out[MO0 + w * 3 + 1] = a1 * INV8SQ;
    out[MO0 + w * 3 + 2] = a2 * INV8SQ;
  }
}

DEV void edge_emb(float d, float emb[16]) {
#pragma unroll
  for (int i = 0; i < 16; ++i) {
    float c = (2.0f * (i + 1)) / 17.0f;
    float df = (d - c) * (17.0f * 0.5f);
    emb[i] = __expf(-df * df) * (4.0f / 1.12f);
  }
}

// h for k in [wv*16, wv*16+16); wv wave-uniform
DEV void radial_hidden16(const float* __restrict__ W1, const float emb[16],
                         int wv, float h[16]) {
#pragma unroll 1
  for (int i = 0; i < 16; ++i) {
    float a = 0.f;
#pragma unroll
    for (int j = 0; j < 16; ++j) a += emb[j] * W1[j * 64 + wv * 16 + i];
    a *= INV16SQ;
    float sig = 1.0f / (1.0f + __expf(-a));
    h[i] = a * sig * HID_SC;
  }
}

DEV void pack16(unsigned short* __restrict__ dst, const float h[16]) {
  unsigned int hw[8];
#pragma unroll
  for (int i = 0; i < 8; ++i)
    hw[i] = (unsigned int)f2bf(h[2 * i]) | ((unsigned int)f2bf(h[2 * i + 1]) << 16);
  uint4 w0 = {hw[0], hw[1], hw[2], hw[3]};
  uint4 w1 = {hw[4], hw[5], hw[6], hw[7]};
  *(uint4*)(dst) = w0;
  *(uint4*)(dst + 8) = w1;
}

// ---------------- weight transposes to bf16 ----------------
__global__ void k_wt(const float* __restrict__ fcv2, unsigned short* __restrict__ wt) {
  int tid = blockIdx.x * blockDim.x + threadIdx.x;
  if (tid >= 2 * 576 * 64) return;
  int l = tid / 36864;
  int r = tid - l * 36864;
  int c = r >> 6;
  int k = r & 63;
  wt[tid] = f2bf(fcv2[l * 36864 + k * 576 + c]);
}

__global__ void k_wtk(const float* __restrict__ fck2, unsigned short* __restrict__ wtk) {
  int tid = blockIdx.x * blockDim.x + threadIdx.x;
  if (tid >= 2 * 288 * 64) return;
  int l = tid / 18432;
  int r = tid - l * 18432;
  int c = r >> 6;
  int k = r & 63;
  wtk[tid] = f2bf(fck2[l * 18432 + k * 288 + c]);
}

// ---------------- CSR build ----------------
__global__ void k_zero_deg(int* __restrict__ deg, int N) {
  int i = blockIdx.x * blockDim.x + threadIdx.x;
  if (i < N) deg[i] = 0;
}

__global__ void k_hist(const int* __restrict__ dstv, int* __restrict__ deg, int E) {
  int e = blockIdx.x * blockDim.x + threadIdx.x;
  if (e < E) atomicAdd(&deg[dstv[e]], 1);
}

__global__ void k_scan(const int* __restrict__ deg, int* __restrict__ rowptr,
                       int* __restrict__ cnt, int N) {
  __shared__ int part[257];
  int tid = threadIdx.x;
  int per = (N + 255) / 256;
  int base = tid * per;
  int s = 0;
  for (int i = 0; i < per; ++i) {
    int idx = base + i;
    if (idx < N) s += deg[idx];
  }
  part[tid + 1] = s;
  if (tid == 0) part[0] = 0;
  __syncthreads();
  if (tid == 0)
    for (int i = 1; i <= 256; ++i) part[i] += part[i - 1];
  __syncthreads();
  int off = part[tid];
  for (int i = 0; i < per; ++i) {
    int idx = base + i;
    if (idx < N) {
      rowptr[idx] = off;
      cnt[idx] = 0;
      off += deg[idx];
    }
  }
  if (tid == 255) rowptr[N] = part[256];
}

__global__ void k_fill(const int* __restrict__ dstv, const int* __restrict__ rowptr,
                       int* __restrict__ cnt, int* __restrict__ col, int E) {
  int e = blockIdx.x * blockDim.x + threadIdx.x;
  if (e >= E) return;
  int t = dstv[e];
  int slot = atomicAdd(&cnt[t], 1);
  col[rowptr[t] + slot] = e;
}

// ---------------- node kernels ----------------
__global__ void k_lin_in(const float* __restrict__ f, const float* __restrict__ W0,
                         const float* __restrict__ W1, float* __restrict__ x, int N) {
  int n = blockIdx.x * blockDim.x + threadIdx.x;
  if (n >= N) return;
  lin_apply<16, 8>(f + n * 40, W0, W1, x + n * 40);
}

__global__ void k_q(const float* __restrict__ x, const float* __restrict__ W0,
                    const float* __restrict__ W1, float* __restrict__ q, int N) {
  int n = blockIdx.x * blockDim.x + threadIdx.x;
  if (n >= N) return;
  lin_apply<8, 4>(x + n * 40, W0, W1, q + n * 20);
}

__global__ void k_update(float* __restrict__ x, const float* __restrict__ agg, int n) {
  int i = blockIdx.x * blockDim.x + threadIdx.x;
  if (i < n) x[i] += agg[i];
}

// ---------------- softmax per node (no atomics) ----------------
__global__ void k_soft(const int* __restrict__ rowptr, const int* __restrict__ col,
                       const float* __restrict__ logit, const float* __restrict__ cutb,
                       float* __restrict__ wgt, int N) {
  int tid = blockIdx.x * blockDim.x + threadIdx.x;
  int n = tid >> 4;
  int sub = tid & 15;
  if (n >= N) return;
  int r0 = rowptr[n], r1 = rowptr[n + 1];

  float m = -INFINITY;
  for (int i = r0 + sub; i < r1; i += 16) m = fmaxf(m, logit[col[i]]);
#pragma unroll
  for (int d = 1; d < 16; d <<= 1) m = fmaxf(m, __shfl_xor(m, d));
  if (m == -INFINITY) m = 0.f;

  float zs = 0.f;
  for (int i = r0 + sub; i < r1; i += 16) {
    int e = col[i];
    zs += cutb[e] * __expf(logit[e] - m);
  }
#pragma unroll
  for (int d = 1; d < 16; d <<= 1) zs += __shfl_xor(zs, d);
  float zz = (zs == 0.f) ? 1.f : zs;
  float inv = 1.f / zz;

  for (int i = r0 + sub; i < r1; i += 16) {
    int e = col[i];
    float ex = cutb[e] * __expf(logit[e] - m);
    wgt[e] = sqrtf(ex * inv + 1e-12f);
  }
}

// =========================================================================
// Weight-stationary edge kernels.
// GEMM is D[cols][64 edges] = W^T @ h^T per 64-edge chunk:
//   A-frag = W^T tile (lane: A[row=c][k=8g+j]) -> address Wt[(16T+c)*64 + 8g]
//            (identical bytes to the old, verified B-frag load)
//   B-frag = h tile   (lane: B[k=8g+j][col=c]) -> h_lds[(16nt+c)*72 + 32ks + 8g]
//   D      : lane holds rows 16T+4g+j, edge col c.
// Wave wv owns col-tiles T = 4t + wv. u-contraction partials are ds_add'ed
// into a per-edge LDS accumulator; per-chunk epilogue finishes.
// =========================================================================

// ---------------- K kernel: logits + cutb ----------------
__global__ void __launch_bounds__(256)
k_edge_k(const float* __restrict__ pos, const float* __restrict__ x,
         const float* __restrict__ q,
         const float* __restrict__ fck1, const unsigned short* __restrict__ wtk,
         const float* __restrict__ dot0, const float* __restrict__ dot1,
         const int* __restrict__ srcv, const int* __restrict__ dstv,
         float* __restrict__ logit, float* __restrict__ cutb, int E) {
  __shared__ alignas(16) unsigned short h_lds[64 * 72];
  __shared__ float fS[48][64];   // fs 0..15 | fv 16..39 | vy 40..47
  __shared__ float y1A[64][4];
  __shared__ float qdA[64][8];
  __shared__ float qvA[64][12];
  __shared__ float accK[64 * 25];  // ks 0..7 | a2 8..11 | a3 12..23

  const int tid = threadIdx.x;
  const int wv = __builtin_amdgcn_readfirstlane(tid >> 6);
  const int lane = tid & 63;
  const int e0 = blockIdx.x * 64;
  const int eL = e0 + lane;
  const bool valid = eL < E;
  const int c = lane & 15, g = lane >> 4, gh = g >> 1;

  // A-frags: 5 col-tiles per wave, T = 4t+wv (clamped into the 18 valid tiles)
  bf16x8 aK[5][2];
#pragma unroll
  for (int t = 0; t < 5; ++t) {
    int T = 4 * t + wv;
    int Tc = (T > 17) ? 17 : T;
    const unsigned short* bs = wtk + (Tc * 16 + c) * 64 + 8 * g;
    aK[t][0] = __builtin_bit_cast(bf16x8, *(const uint4*)(bs));
    aK[t][1] = __builtin_bit_cast(bf16x8, *(const uint4*)(bs + 32));
  }

  int s = valid ? srcv[eL] : 0, t_ = valid ? dstv[eL] : 0;

  float y1v[3], d;
  {
    float vx = pos[s * 3 + 0] - pos[t_ * 3 + 0];
    float vy_ = pos[s * 3 + 1] - pos[t_ * 3 + 1];
    float vz = pos[s * 3 + 2] - pos[t_ * 3 + 2];
    d = sqrtf(vx * vx + vy_ * vy_ + vz * vz + 1e-24f);
    float inv = SQ3F / d;
    y1v[0] = vx * inv; y1v[1] = vy_ * inv; y1v[2] = vz * inv;
  }
  float emb[16];
  edge_emb(d, emb);
  {
    float h[16];
    radial_hidden16(fck1, emb, wv, h);
    pack16(&h_lds[lane * 72 + 16 * wv], h);
  }

  for (int i = tid; i < 64 * 25; i += 256) accK[i] = 0.f;

  if (wv == 0) {
    const float* xs = x + s * 40;
    float fvl[24];
#pragma unroll
    for (int i = 0; i < 16; ++i) fS[i][lane] = xs[i];
#pragma unroll
    for (int i = 0; i < 24; ++i) { fvl[i] = xs[16 + i]; fS[16 + i][lane] = fvl[i]; }
#pragma unroll
    for (int u = 0; u < 8; ++u)
      fS[40 + u][lane] = (fvl[u * 3] * y1v[0] + fvl[u * 3 + 1] * y1v[1] +
                          fvl[u * 3 + 2] * y1v[2]) * INV_SQ3F;
    y1A[lane][0] = y1v[0]; y1A[lane][1] = y1v[1]; y1A[lane][2] = y1v[2];
    if (valid) {
      float uu = 10.0f * (1.0f - 0.5f * d);
      cutb[eL] = (uu > 0.f) ? __expf(-1.0f / fmaxf(uu, 1e-9f)) : 0.f;
    }
    const float* qd_ = q + t_ * 20;
    float qs_[8], qv_[12];
#pragma unroll
    for (int u = 0; u < 8; ++u) qs_[u] = qd_[u];
#pragma unroll
    for (int i = 0; i < 12; ++i) qv_[i] = qd_[8 + i];
#pragma unroll
    for (int v = 0; v < 8; ++v) {
      float a = 0.f;
#pragma unroll
      for (int u = 0; u < 8; ++u) a += qs_[u] * dot0[u * 8 + v];
      qdA[lane][v] = a * (FAN_DOT * FAN_TP);
    }
#pragma unroll
    for (int v = 0; v < 4; ++v)
#pragma unroll
      for (int i = 0; i < 3; ++i) {
        float a = 0.f;
#pragma unroll
        for (int u = 0; u < 4; ++u) a += qv_[u * 3 + i] * dot1[u * 4 + v];
        qvA[lane][v * 3 + i] = a * (FAN_DOT * INV_SQ3F);
      }
  }
  __syncthreads();

  const f32x4 zero4 = {0.f, 0.f, 0.f, 0.f};

#pragma unroll
  for (int nt = 0; nt < 4; ++nt) {
    const int e = 16 * nt + c;   // block-local edge this lane produces for
    bf16x8 bh0 = __builtin_bit_cast(bf16x8, *(const uint4*)&h_lds[e * 72 + 8 * g]);
    bf16x8 bh1 = __builtin_bit_cast(bf16x8, *(const uint4*)&h_lds[e * 72 + 32 + 8 * g]);

    float ksP[4] = {0.f, 0.f, 0.f, 0.f};
    float a2P[4] = {0.f, 0.f, 0.f, 0.f};
    float a3P[4][3] = {{0.f}};

#pragma unroll
    for (int t = 0; t < 5; ++t) {
      f32x4 acc = __builtin_amdgcn_mfma_f32_16x16x32_bf16(aK[t][0], bh0, zero4, 0, 0, 0);
      acc = __builtin_amdgcn_mfma_f32_16x16x32_bf16(aK[t][1], bh1, acc, 0, 0, 0);
      if (t < 2) {                     // W1k: u = 2T + gh = 8t + 2wv + gh
        int u = 8 * t + 2 * wv + gh;
#pragma unroll
        for (int j = 0; j < 4; ++j) ksP[j] += fS[u][e] * acc[j];
      } else if (t == 2) {             // W2k: u = 4wv + g
        int u = 4 * wv + g;
#pragma unroll
        for (int j = 0; j < 4; ++j) a2P[j] += fS[u][e] * acc[j];
      } else if (t == 3) {
        if (wv < 2) {                  // W3k: u = 4wv + g
          int u = 4 * wv + g;
#pragma unroll
          for (int j = 0; j < 4; ++j)
#pragma unroll
            for (int i = 0; i < 3; ++i) a3P[j][i] += fS[16 + 3 * u + i][e] * acc[j];
        } else {                       // W4k (T=14,15): u = 2(wv-2) + gh
          int u = 2 * (wv - 2) + gh;
#pragma unroll
          for (int j = 0; j < 4; ++j) ksP[j] += fS[40 + u][e] * acc[j];
        }
      } else {                         // t == 4
        if (wv < 2) {                  // W4k (T=16,17): u = 2(wv+2) + gh
          int u = 2 * (wv + 2) + gh;
#pragma unroll
          for (int j = 0; j < 4; ++j) ksP[j] += fS[40 + u][e] * acc[j];
        }                              // wv>=2: pad tile, skip
      }
    }

    const int sb = (4 * g) & 7;
    float* aB = accK + e * 25;
#pragma unroll
    for (int j = 0; j < 4; ++j) atomicAdd(&aB[sb + j], ksP[j]);
#pragma unroll
    for (int j = 0; j < 4; ++j) atomicAdd(&aB[8 + j], a2P[j]);
#pragma unroll
    for (int j = 0; j < 4; ++j)
#pragma unroll
      for (int i = 0; i < 3; ++i) atomicAdd(&aB[12 + 3 * j + i], a3P[j][i]);
  }
  __syncthreads();

  // epilogue: one thread per edge
  if (tid < 64) {
    int ee = e0 + tid;
    if (ee < E) {
      const float* a = accK + tid * 25;
      float lg = 0.f;
#pragma unroll
      for (int v = 0; v < 8; ++v) lg += a[v] * qdA[tid][v];
#pragma unroll
      for (int v = 0; v < 4; ++v)
#pragma unroll
        for (int i = 0; i < 3; ++i) {
          float kv = a[8 + v] * y1A[tid][i] * FAN_TP + a[12 + 3 * v + i] * FAN_TP_V;
          lg += kv * qvA[tid][v * 3 + i];
        }
      logit[ee] = lg;
    }
  }
}

// ---------------- V kernel: unweighted val[e][40] ----------------
__global__ void __launch_bounds__(256)
k_edge_v(const float* __restrict__ pos, const float* __restrict__ x,
         const float* __restrict__ fcv1, const unsigned short* __restrict__ wtv,
         const int* __restrict__ srcv, const int* __restrict__ dstv,
         __hip_bfloat16* __restrict__ val, int E) {
  __shared__ alignas(16) unsigned short h_lds[64 * 72];
  __shared__ float fS[48][64];
  __shared__ float y1A[64][4];
  __shared__ float accL[64 * 49];  // vs 0..15 | b2 16..23 | b3 24..47

  const int tid = threadIdx.x;
  const int wv = __builtin_amdgcn_readfirstlane(tid >> 6);
  const int lane = tid & 63;
  const int e0 = blockIdx.x * 64;
  const int eL = e0 + lane;
  const bool valid = eL < E;
  const int c = lane & 15, g = lane >> 4, gh = g >> 1;

  // A-frags: 9 col-tiles per wave, T = 4t + wv (exactly 36 tiles)
  bf16x8 aW[9][2];
#pragma unroll
  for (int t = 0; t < 9; ++t) {
    int T = 4 * t + wv;
    const unsigned short* bs = wtv + (T * 16 + c) * 64 + 8 * g;
    aW[t][0] = __builtin_bit_cast(bf16x8, *(const uint4*)(bs));
    aW[t][1] = __builtin_bit_cast(bf16x8, *(const uint4*)(bs + 32));
  }

  int s = valid ? srcv[eL] : 0, t_ = valid ? dstv[eL] : 0;

  float y1v[3], d;
  {
    float vx = pos[s * 3 + 0] - pos[t_ * 3 + 0];
    float vy_ = pos[s * 3 + 1] - pos[t_ * 3 + 1];
    float vz = pos[s * 3 + 2] - pos[t_ * 3 + 2];
    d = sqrtf(vx * vx + vy_ * vy_ + vz * vz + 1e-24f);
    float inv = SQ3F / d;
    y1v[0] = vx * inv; y1v[1] = vy_ * inv; y1v[2] = vz * inv;
  }
  float emb[16];
  edge_emb(d, emb);
  {
    float h[16];
    radial_hidden16(fcv1, emb, wv, h);
    pack16(&h_lds[lane * 72 + 16 * wv], h);
  }

  for (int i = tid; i < 64 * 49; i += 256) accL[i] = 0.f;

  if (wv == 0) {
    const float* xs = x + s * 40;
    float fvl[24];
#pragma unroll
    for (int i = 0; i < 16; ++i) fS[i][lane] = xs[i];
#pragma unroll
    for (int i = 0; i < 24; ++i) { fvl[i] = xs[16 + i]; fS[16 + i][lane] = fvl[i]; }
#pragma unroll
    for (int u = 0; u < 8; ++u)
      fS[40 + u][lane] = (fvl[u * 3] * y1v[0] + fvl[u * 3 + 1] * y1v[1] +
                          fvl[u * 3 + 2] * y1v[2]) * INV_SQ3F;
    y1A[lane][0] = y1v[0]; y1A[lane][1] = y1v[1]; y1A[lane][2] = y1v[2];
  }
  __syncthreads();

  const f32x4 zero4 = {0.f, 0.f, 0.f, 0.f};

#pragma unroll
  for (int nt = 0; nt < 4; ++nt) {
    const int e = 16 * nt + c;
    bf16x8 bh0 = __builtin_bit_cast(bf16x8, *(const uint4*)&h_lds[e * 72 + 8 * g]);
    bf16x8 bh1 = __builtin_bit_cast(bf16x8, *(const uint4*)&h_lds[e * 72 + 32 + 8 * g]);

    float vsP[4] = {0.f, 0.f, 0.f, 0.f};
    float b2P[4] = {0.f, 0.f, 0.f, 0.f};
    float b3P[4][3] = {{0.f}};

#pragma unroll
    for (int t = 0; t < 9; ++t) {
      f32x4 acc = __builtin_amdgcn_mfma_f32_16x16x32_bf16(aW[t][0], bh0, zero4, 0, 0, 0);
      acc = __builtin_amdgcn_mfma_f32_16x16x32_bf16(aW[t][1], bh1, acc, 0, 0, 0);
      if (t < 4) {                     // W1: u = T = 4t + wv
        int u = 4 * t + wv;
#pragma unroll
        for (int j = 0; j < 4; ++j) vsP[j] += fS[u][e] * acc[j];
      } else if (t < 6) {              // W2: u = 2(T-16) + gh
        int u = 2 * (4 * t + wv - 16) + gh;
#pragma unroll
        for (int j = 0; j < 4; ++j) b2P[j] += fS[u][e] * acc[j];
      } else if (t == 6) {             // W3: u = 2(T-24) + gh = 2wv + gh
        int u = 2 * wv + gh;
#pragma unroll
        for (int j = 0; j < 4; ++j)
#pragma unroll
          for (int i = 0; i < 3; ++i) b3P[j][i] += fS[16 + 3 * u + i][e] * acc[j];
      } else {                         // W4: u = T - 28 = 4(t-7) + wv
        int u = 4 * (t - 7) + wv;
#pragma unroll
        for (int j = 0; j < 4; ++j) vsP[j] += fS[40 + u][e] * acc[j];
      }
    }

    const int sb = (4 * g) & 7;
    float* aB = accL + e * 49;
#pragma unroll
    for (int j = 0; j < 4; ++j) atomicAdd(&aB[4 * g + j], vsP[j]);
#pragma unroll
    for (int j = 0; j < 4; ++j) atomicAdd(&aB[16 + sb + j], b2P[j]);
#pragma unroll
    for (int j = 0; j < 4; ++j)
#pragma unroll
      for (int i = 0; i < 3; ++i) atomicAdd(&aB[24 + 3 * (sb + j) + i], b3P[j][i]);
  }
  __syncthreads();

  // epilogue: 4 threads per edge, thread p writes outputs [10p, 10p+10)
  {
    int ep = tid >> 2, p = tid & 3;
    int ee = e0 + ep;
    if (ee < E) {
      const float* aL = accL + ep * 49;
      __hip_bfloat16* vr = val + (size_t)ee * 40;
      float yy[3] = {y1A[ep][0], y1A[ep][1], y1A[ep][2]};
#pragma unroll
      for (int q2 = 0; q2 < 10; ++q2) {
        int idx = p * 10 + q2;
        float v;
        if (idx < 16) {
          v = aL[idx] * FAN_TP;
        } else {
          int k = idx - 16;
          int w = (k * 86) >> 8;       // k/3 for k<24
          int i = k - 3 * w;
          v = aL[16 + w] * yy[i] * FAN_TP + aL[24 + k] * FAN_TP_V;
        }
        vr[idx] = __float2bfloat16(v);
      }
    }
  }
}

// ---------------- gather: agg[n] = sum_e wgt[e]*val[e] ----------------
__global__ void k_gather(const int* __restrict__ rowptr, const int* __restrict__ col,
                         const float* __restrict__ wgt,
                         const __hip_bfloat16* __restrict__ val,
                         float* __restrict__ agg, int N) {
  int wid = (blockIdx.x * blockDim.x + threadIdx.x) >> 6;
  int lane = threadIdx.x & 63;
  if (wid >= N || lane >= 40) return;
  int r0 = rowptr[wid], r1 = rowptr[wid + 1];
  float acc = 0.f;
  for (int i = r0; i < r1; ++i) {
    int e = col[i];
    acc += wgt[e] * __bfloat162float(val[(size_t)e * 40 + lane]);
  }
  agg[(size_t)wid * 40 + lane] = acc;
}

// ---------------- output kernel ----------------
template <bool BF>
__global__ void k_out(const float* __restrict__ x, const float* __restrict__ rb0,
                      const float* __restrict__ rb1, const float* __restrict__ re0,
                      const float* __restrict__ re1, void* __restrict__ out, int N,
                      const int* __restrict__ flag) {
  if ((*flag != 0) != BF) return;
  int n = blockIdx.x * blockDim.x + threadIdx.x;
  if (n >= N) return;
  float b[20], eta[20];
  lin_apply<8, 4>(x + n * 40, rb0, rb1, b);
  lin_apply<8, 4>(x + n * 40, re0, re1, eta);
  if (BF) {
    __hip_bfloat16* o = (__hip_bfloat16*)out;
#pragma unroll
    for (int j = 0; j < 20; ++j) o[n * 20 + j] = __float2bfloat16(b[j]);
#pragma unroll
    for (int j = 0; j < 20; ++j) o[N * 20 + n * 20 + j] = __float2bfloat16(eta[j]);
  } else {
    float* o = (float*)out;
#pragma unroll
    for (int j = 0; j < 20; ++j) o[n * 20 + j] = b[j];
#pragma unroll
    for (int j = 0; j < 20; ++j) o[N * 20 + n * 20 + j] = eta[j];
  }
}

// ---------------- host ----------------
extern "C" void kernel_launch(void* const* d_in, const int* in_sizes, int n_in,
                              void* d_out, int out_size, void* d_ws, size_t ws_size,
                              hipStream_t stream) {
  float* ws = (float*)d_ws;
  const int N = in_sizes[0] / 40;
  const int E = in_sizes[16];
  const int* src = (const int*)d_in[16];
  const int* dst = (const int*)d_in[17];
  int* flag = (int*)(ws + OFF_FLAG);
  unsigned short* wtv = (unsigned short*)(ws + OFF_WT);
  unsigned short* wtk = (unsigned short*)(ws + OFF_WTK);
  int* col = (int*)(ws + OFF_COL);
  int* rowptr = (int*)(ws + OFF_ROWP);
  int* deg = (int*)(ws + OFF_DEG);
  int* cnt = (int*)(ws + OFF_CNT);
  __hip_bfloat16* val = (__hip_bfloat16*)(ws + OFF_VAL);

  k_detect<<<1, 64, 0, stream>>>((const unsigned int*)d_in[0], flag);

  CvtArgs ca;
  const int order[16] = {2, 3, 4, 5, 6, 7, 8, 9, 10, 11, 12, 13, 14, 15, 0, 1};
  const int offs[16] = {OFF_LIN0, OFF_LIN1, OFF_HQ0, OFF_HQ1, OFF_FCK1, OFF_FCK2,
                        OFF_FCV1, OFF_FCV2, OFF_DOT0, OFF_DOT1, OFF_RB0, OFF_RB1,
                        OFF_RE0, OFF_RE1, OFF_F, OFF_POS};
  for (int i = 0; i < 16; ++i) {
    ca.src[i] = d_in[order[i]];
    ca.n[i] = in_sizes[order[i]];
    ca.off[i] = offs[i];
  }
  k_cvt<false><<<512, 256, 0, stream>>>(ca, ws, flag);
  k_cvt<true><<<512, 256, 0, stream>>>(ca, ws, flag);
  k_wt<<<(2 * 576 * 64 + 255) / 256, 256, 0, stream>>>(ws + OFF_FCV2, wtv);
  k_wtk<<<(2 * 288 * 64 + 255) / 256, 256, 0, stream>>>(ws + OFF_FCK2, wtk);

  // CSR build (dst static per launch)
  k_zero_deg<<<(N + 255) / 256, 256, 0, stream>>>(deg, N);
  k_hist<<<(E + 255) / 256, 256, 0, stream>>>(dst, deg, E);
  k_scan<<<1, 256, 0, stream>>>(deg, rowptr, cnt, N);
  k_fill<<<(E + 255) / 256, 256, 0, stream>>>(dst, rowptr, cnt, col, E);

  float* x = ws + OFF_X;
  float* q = ws + OFF_Q;
  float* agg = ws + OFF_AGG;
  float* logit = ws + OFF_LOGIT;
  float* cutb = ws + OFF_CUT;
  float* wgtb = ws + OFF_WGT;
  const float* pos = ws + OFF_POS;

  const int nodeBlocks = (N + 255) / 256;
  const int vecBlocks = (N * 40 + 255) / 256;
  const int eb64 = (E + 63) / 64;
  const int softBlocks = (N * 16 + 255) / 256;
  const int gatherBlocks = (N * 64 + 255) / 256;

  k_lin_in<<<nodeBlocks, 256, 0, stream>>>(ws + OFF_F, ws + OFF_LIN0, ws + OFF_LIN1, x, N);

  for (int l = 0; l < 2; ++l) {
    k_q<<<nodeBlocks, 256, 0, stream>>>(x, ws + OFF_HQ0 + l * 128, ws + OFF_HQ1 + l * 32, q, N);
    k_edge_k<<<eb64, 256, 0, stream>>>(
        pos, x, q, ws + OFF_FCK1 + l * 1024, wtk + l * 18432,
        ws + OFF_DOT0 + l * 64, ws + OFF_DOT1 + l * 16, src, dst, logit, cutb, E);
    k_soft<<<softBlocks, 256, 0, stream>>>(rowptr, col, logit, cutb, wgtb, N);
    k_edge_v<<<eb64, 256, 0, stream>>>(
        pos, x, ws + OFF_FCV1 + l * 1024, wtv + l * 36864, src, dst, val, E);
    k_gather<<<gatherBlocks, 256, 0, stream>>>(rowptr, col, wgtb, val, agg, N);
    k_update<<<vecBlocks, 256, 0, stream>>>(x, agg, N * 40);
  }

  k_out<false><<<nodeBlocks, 256, 0, stream>>>(x, ws + OFF_RB0, ws + OFF_RB1,
                                               ws + OFF_RE0, ws + OFF_RE1, d_out, N, flag);
  k_out<true><<<nodeBlocks, 256, 0, stream>>>(x, ws + OFF_RB0, ws + OFF_RB1,
                                              ws + OFF_RE0, ws + OFF_RE1, d_out, N, flag);
}

// Round 9
// 468.911 us; speedup vs baseline: 2.2166x; 2.2166x over previous
//
#include <hip/hip_runtime.h>
#include <hip/hip_bf16.h>
#include <math.h>

#define DEV __device__ __forceinline__

typedef __attribute__((ext_vector_type(4))) float f32x4;
typedef __attribute__((ext_vector_type(8))) __bf16 bf16x8;

// ---------------- problem constants ----------------
constexpr int N_CONST = 8192;
constexpr int E_CONST = 131072;

constexpr float SQ3F     = 1.7320508075688772f;
constexpr float INV_SQ3F = 0.57735026918962576f;
constexpr float FAN_TP   = 0.20412414523193150f;   // 24^-0.5
constexpr float FAN_TP_V = 0.35355339059327373f;   // sqrt(3)*24^-0.5
constexpr float FAN_DOT  = 0.11180339887498949f;   // 80^-0.5
constexpr float INV16SQ  = 0.25f;                  // 16^-0.5
constexpr float INV8SQ   = 0.35355339059327373f;   // 8^-0.5
constexpr float HID_SC   = 0.125f;                 // 64^-0.5

// ---------------- workspace layout (float offsets) ----------------
enum : int {
  OFF_LIN0 = 0,
  OFF_LIN1 = OFF_LIN0 + 256,
  OFF_HQ0  = OFF_LIN1 + 64,
  OFF_HQ1  = OFF_HQ0 + 256,
  OFF_FCK1 = OFF_HQ1 + 64,
  OFF_FCK2 = OFF_FCK1 + 2048,
  OFF_FCV1 = OFF_FCK2 + 36864,
  OFF_FCV2 = OFF_FCV1 + 2048,
  OFF_DOT0 = OFF_FCV2 + 73728,
  OFF_DOT1 = OFF_DOT0 + 128,
  OFF_RB0  = OFF_DOT1 + 32,
  OFF_RB1  = OFF_RB0 + 128,
  OFF_RE0  = OFF_RB1 + 32,
  OFF_RE1  = OFF_RE0 + 128,
  OFF_F    = OFF_RE1 + 32,
  OFF_POS  = OFF_F + N_CONST * 40,
  OFF_X    = OFF_POS + N_CONST * 3,
  OFF_Q    = OFF_X + N_CONST * 40,
  OFF_MX   = OFF_Q + N_CONST * 20,
  OFF_Z    = OFF_MX + N_CONST,
  OFF_AGG  = OFF_Z + N_CONST,
  OFF_LOGIT= OFF_AGG + N_CONST * 40,
  OFF_CUT  = OFF_LOGIT + E_CONST,
  OFF_EX   = OFF_CUT + E_CONST,
  OFF_FLAG = OFF_EX + E_CONST,     // int flag in a float slot
  OFF_WT   = (OFF_FLAG + 7) & ~3,  // bf16 WtV [2][576][64]
  OFF_WTK  = OFF_WT + 36864,       // bf16 WtK [2][288][64]
};

// ---------------- dtype detection ----------------
__global__ void k_detect(const unsigned int* __restrict__ words, int* __restrict__ flag) {
  if (blockIdx.x != 0 || threadIdx.x != 0) return;
  int cnt = 0;
  for (int i = 0; i < 512; ++i) {
    unsigned b = (words[i] >> 8) & 0x7Fu;
    cnt += (b >= 0x3Au && b <= 0x43u) ? 1 : 0;
  }
  *flag = (cnt > 256) ? 1 : 0;
}

// ---------------- convert all float inputs to f32 in ws ----------------
struct CvtArgs {
  const void* src[16];
  int n[16];
  int off[16];
};

template <bool BF>
__global__ void k_cvt(CvtArgs a, float* __restrict__ ws, const int* __restrict__ flag) {
  if ((*flag != 0) != BF) return;
  int tid = blockIdx.x * blockDim.x + threadIdx.x;
  int stride = gridDim.x * blockDim.x;
  for (int arr = 0; arr < 16; ++arr) {
    float* dst = ws + a.off[arr];
    int n = a.n[arr];
    if (BF) {
      const __hip_bfloat16* s = (const __hip_bfloat16*)a.src[arr];
      for (int i = tid; i < n; i += stride) dst[i] = __bfloat162float(s[i]);
    } else {
      const float* s = (const float*)a.src[arr];
      for (int i = tid; i < n; i += stride) dst[i] = s[i];
    }
  }
}

// ---------------- helpers ----------------
DEV unsigned short f2bf(float f) {   // RNE f32 -> bf16 bits
  unsigned int u = __float_as_uint(f);
  u = u + 0x7FFFu + ((u >> 16) & 1u);
  return (unsigned short)(u >> 16);
}

DEV void atomicMaxF(float* addr, float val) {
  unsigned int* ai = (unsigned int*)addr;
  unsigned int old = *ai;
  while (__uint_as_float(old) < val) {
    unsigned int assumed = old;
    old = atomicCAS(ai, assumed, __float_as_uint(val));
    if (old == assumed) break;
  }
}

template <int MO0, int MO1>
DEV void lin_apply(const float* __restrict__ in40, const float* __restrict__ W0,
                   const float* __restrict__ W1, float* __restrict__ out) {
#pragma unroll
  for (int j = 0; j < MO0; ++j) {
    float a = 0.f;
#pragma unroll
    for (int i = 0; i < 16; ++i) a += in40[i] * W0[i * MO0 + j];
    out[j] = a * INV16SQ;
  }
#pragma unroll
  for (int w = 0; w < MO1; ++w) {
    float a0 = 0.f, a1 = 0.f, a2 = 0.f;
#pragma unroll
    for (int u = 0; u < 8; ++u) {
      float wt = W1[u * MO1 + w];
      a0 += in40[16 + u * 3 + 0] * wt;
      a1 += in40[16 + u * 3 + 1] * wt;
      a2 += in40[16 + u * 3 + 2] * wt;
    }
    out[MO0 + w * 3 + 0] = a0 * INV8SQ;
    out[MO0 + w * 3 + 1] = a1 * INV8SQ;
    out[MO0 + w * 3 + 2] = a2 * INV8SQ;
  }
}

DEV void edge_emb(float d, float emb[16]) {
#pragma unroll
  for (int i = 0; i < 16; ++i) {
    float c = (2.0f * (i + 1)) / 17.0f;
    float df = (d - c) * (17.0f * 0.5f);
    emb[i] = __expf(-df * df) * (4.0f / 1.12f);
  }
}

// h for k in [khalf*32, khalf*32+32); khalf wave-uniform
DEV void radial_hidden32(const float* __restrict__ W1, const float emb[16],
                         int khalf, float h[32]) {
#pragma unroll 4
  for (int i = 0; i < 32; ++i) {
    float a = 0.f;
#pragma unroll
    for (int j = 0; j < 16; ++j) a += emb[j] * W1[j * 64 + khalf * 32 + i];
    a *= INV16SQ;
    float sig = 1.0f / (1.0f + __expf(-a));
    h[i] = a * sig * HID_SC;
  }
}

DEV void pack32(unsigned short* __restrict__ dst, const float h[32]) {
  unsigned int hw[16];
#pragma unroll
  for (int i = 0; i < 16; ++i)
    hw[i] = (unsigned int)f2bf(h[2 * i]) | ((unsigned int)f2bf(h[2 * i + 1]) << 16);
#pragma unroll
  for (int qq = 0; qq < 4; ++qq) {
    uint4 w = {hw[4 * qq], hw[4 * qq + 1], hw[4 * qq + 2], hw[4 * qq + 3]};
    *(uint4*)(dst + 8 * qq) = w;
  }
}

// ---------------- weight transposes to bf16 ----------------
__global__ void k_wt(const float* __restrict__ fcv2, unsigned short* __restrict__ wt) {
  int tid = blockIdx.x * blockDim.x + threadIdx.x;
  if (tid >= 2 * 576 * 64) return;
  int l = tid / 36864;
  int r = tid - l * 36864;
  int c = r >> 6;
  int k = r & 63;
  wt[tid] = f2bf(fcv2[l * 36864 + k * 576 + c]);
}

__global__ void k_wtk(const float* __restrict__ fck2, unsigned short* __restrict__ wtk) {
  int tid = blockIdx.x * blockDim.x + threadIdx.x;
  if (tid >= 2 * 288 * 64) return;
  int l = tid / 18432;
  int r = tid - l * 18432;
  int c = r >> 6;
  int k = r & 63;
  wtk[tid] = f2bf(fck2[l * 18432 + k * 288 + c]);
}

// ---------------- node kernels ----------------
__global__ void k_lin_in(const float* __restrict__ f, const float* __restrict__ W0,
                         const float* __restrict__ W1, float* __restrict__ x, int N) {
  int n = blockIdx.x * blockDim.x + threadIdx.x;
  if (n >= N) return;
  lin_apply<16, 8>(f + n * 40, W0, W1, x + n * 40);
}

__global__ void k_q(const float* __restrict__ x, const float* __restrict__ W0,
                    const float* __restrict__ W1, float* __restrict__ q, int N) {
  int n = blockIdx.x * blockDim.x + threadIdx.x;
  if (n >= N) return;
  lin_apply<8, 4>(x + n * 40, W0, W1, q + n * 20);
}

__global__ void k_init(float* __restrict__ mx, float* __restrict__ z,
                       float* __restrict__ agg, int N) {
  int i = blockIdx.x * blockDim.x + threadIdx.x;
  if (i < N * 40) agg[i] = 0.f;
  if (i < N) { mx[i] = -INFINITY; z[i] = 0.f; }
}

__global__ void k_update(float* __restrict__ x, const float* __restrict__ agg, int n) {
  int i = blockIdx.x * blockDim.x + threadIdx.x;
  if (i < n) x[i] += agg[i];
}

// ---------------- edge kernel 2: exp + denominator ----------------
__global__ void k_edge_ex(const int* __restrict__ dstv, const float* __restrict__ logit,
                          const float* __restrict__ cutb, const float* __restrict__ mx,
                          float* __restrict__ ex, float* __restrict__ z, int E) {
  int e = blockIdx.x * blockDim.x + threadIdx.x;
  if (e >= E) return;
  int t = dstv[e];
  float m = mx[t];
  if (m == -INFINITY) m = 0.f;
  float v = cutb[e] * __expf(logit[e] - m);
  ex[e] = v;
  atomicAdd(&z[t], v);
}

// =========================================================================
// Edge kernels: round-5 verified structure, 2 waves/block, 2 M-tiles/wave.
// Block = 128 threads = 2 waves, 64 edges. Wave wv owns rows [32wv, 32wv+32).
// Each B-fragment load feeds 4 MFMAs (2 M-tiles x 2 K-steps).
// =========================================================================

// ---------------- edge kernel 1: K path + logits ----------------
__global__ void __launch_bounds__(128)
k_edge_k(const float* __restrict__ pos, const float* __restrict__ x,
         const float* __restrict__ q,
         const float* __restrict__ fck1, const unsigned short* __restrict__ wtk,
         const float* __restrict__ dot0, const float* __restrict__ dot1,
         const int* __restrict__ srcv, const int* __restrict__ dstv,
         float* __restrict__ logit, float* __restrict__ cutb,
         float* __restrict__ mx, int E) {
  __shared__ alignas(16) unsigned short h_lds[64 * 72];  // [edge][k] stride 72
  __shared__ float fS[48][64];   // fs 0..15 | fv 16..39 | vy 40..47
  __shared__ float y1A[64][4];
  __shared__ float qdA[64][8];
  __shared__ float qvA[64][12];
  __shared__ int dstA[64];

  const int tid = threadIdx.x;
  const int wv = __builtin_amdgcn_readfirstlane(tid >> 6);
  const int lane = tid & 63;
  const int e0 = blockIdx.x * 64;
  const int eL = e0 + lane;
  const bool valid = eL < E;

  int s = valid ? srcv[eL] : 0, t = valid ? dstv[eL] : 0;

  float y1v[3], d;
  {
    float vx = pos[s * 3 + 0] - pos[t * 3 + 0];
    float vy_ = pos[s * 3 + 1] - pos[t * 3 + 1];
    float vz = pos[s * 3 + 2] - pos[t * 3 + 2];
    d = sqrtf(vx * vx + vy_ * vy_ + vz * vz + 1e-24f);
    float inv = SQ3F / d;
    y1v[0] = vx * inv; y1v[1] = vy_ * inv; y1v[2] = vz * inv;
  }
  float emb[16];
  edge_emb(d, emb);
  {
    float h[32];
    radial_hidden32(fck1, emb, wv, h);
    pack32(&h_lds[lane * 72 + 32 * wv], h);
  }

  if (wv == 0) {
    const float* xs = x + s * 40;
    float fvl[24];
#pragma unroll
    for (int i = 0; i < 16; ++i) fS[i][lane] = xs[i];
#pragma unroll
    for (int i = 0; i < 24; ++i) { fvl[i] = xs[16 + i]; fS[16 + i][lane] = fvl[i]; }
#pragma unroll
    for (int u = 0; u < 8; ++u)
      fS[40 + u][lane] = (fvl[u * 3] * y1v[0] + fvl[u * 3 + 1] * y1v[1] +
                          fvl[u * 3 + 2] * y1v[2]) * INV_SQ3F;
    y1A[lane][0] = y1v[0]; y1A[lane][1] = y1v[1]; y1A[lane][2] = y1v[2];
    dstA[lane] = t;
    if (valid) {
      float uu = 10.0f * (1.0f - 0.5f * d);
      cutb[eL] = (uu > 0.f) ? __expf(-1.0f / fmaxf(uu, 1e-9f)) : 0.f;
    }
    const float* qd_ = q + t * 20;
    float qs_[8], qv_[12];
#pragma unroll
    for (int u = 0; u < 8; ++u) qs_[u] = qd_[u];
#pragma unroll
    for (int i = 0; i < 12; ++i) qv_[i] = qd_[8 + i];
#pragma unroll
    for (int v = 0; v < 8; ++v) {
      float a = 0.f;
#pragma unroll
      for (int u = 0; u < 8; ++u) a += qs_[u] * dot0[u * 8 + v];
      qdA[lane][v] = a * (FAN_DOT * FAN_TP);
    }
#pragma unroll
    for (int v = 0; v < 4; ++v)
#pragma unroll
      for (int i = 0; i < 3; ++i) {
        float a = 0.f;
#pragma unroll
        for (int u = 0; u < 4; ++u) a += qv_[u * 3 + i] * dot1[u * 4 + v];
        qvA[lane][v * 3 + i] = a * (FAN_DOT * INV_SQ3F);
      }
  }
  __syncthreads();

  const int c = lane & 15, g = lane >> 4;
  const f32x4 zero4 = {0.f, 0.f, 0.f, 0.f};

  bf16x8 aK[2][2];
#pragma unroll
  for (int m = 0; m < 2; ++m)
#pragma unroll
    for (int ks = 0; ks < 2; ++ks)
      aK[m][ks] = __builtin_bit_cast(
          bf16x8, *(const uint4*)&h_lds[(32 * wv + 16 * m + c) * 72 + 32 * ks + 8 * g]);

  float ksp[2][4] = {{0.f}}, a2p[2][4] = {{0.f}}, a3p[2][4][3] = {{{0.f}}};

#pragma unroll
  for (int T = 0; T < 18; ++T) {
    const unsigned short* bs = wtk + (T * 16 + c) * 64 + 8 * g;
    bf16x8 b0 = __builtin_bit_cast(bf16x8, *(const uint4*)(bs));
    bf16x8 b1 = __builtin_bit_cast(bf16x8, *(const uint4*)(bs + 32));
#pragma unroll
    for (int m = 0; m < 2; ++m) {
      f32x4 acc = __builtin_amdgcn_mfma_f32_16x16x32_bf16(aK[m][0], b0, zero4, 0, 0, 0);
      acc = __builtin_amdgcn_mfma_f32_16x16x32_bf16(aK[m][1], b1, acc, 0, 0, 0);
      const int rb = 32 * wv + 16 * m + 4 * g;
      if (T < 8) {
        int u = 2 * T + (c >> 3);
#pragma unroll
        for (int j = 0; j < 4; ++j) ksp[m][j] += fS[u][rb + j] * acc[j];
      } else if (T < 12) {
        int u = 4 * (T - 8) + (c >> 2);
#pragma unroll
        for (int j = 0; j < 4; ++j) a2p[m][j] += fS[u][rb + j] * acc[j];
      } else if (T < 14) {
        int u = 4 * (T - 12) + (c >> 2);
#pragma unroll
        for (int j = 0; j < 4; ++j)
#pragma unroll
          for (int i = 0; i < 3; ++i) a3p[m][j][i] += fS[16 + u * 3 + i][rb + j] * acc[j];
      } else {
        int u = 2 * (T - 14) + (c >> 3);
#pragma unroll
        for (int j = 0; j < 4; ++j) ksp[m][j] += fS[40 + u][rb + j] * acc[j];
      }
    }
  }

#pragma unroll
  for (int m = 0; m < 2; ++m) {
    float ksf[4], a2f[4], a3f[4][3];
#pragma unroll
    for (int j = 0; j < 4; ++j) ksf[j] = ksp[m][j] + __shfl_xor(ksp[m][j], 8);
#pragma unroll
    for (int j = 0; j < 4; ++j) {
      float v = a2p[m][j] + __shfl_xor(a2p[m][j], 4);
      a2f[j] = v + __shfl_xor(v, 8);
    }
#pragma unroll
    for (int j = 0; j < 4; ++j)
#pragma unroll
      for (int i = 0; i < 3; ++i) {
        float v = a3p[m][j][i] + __shfl_xor(a3p[m][j][i], 4);
        a3f[j][i] = v + __shfl_xor(v, 8);
      }

    float lgp[4];
#pragma unroll
    for (int j = 0; j < 4; ++j) {
      int er = 32 * wv + 16 * m + 4 * g + j;
      float a = 0.f;
      if (c < 8) {
        a = ksf[j] * qdA[er][c];
      } else if (c < 12) {
        int w = c - 8;
#pragma unroll
        for (int i = 0; i < 3; ++i)
          a += (a2f[j] * y1A[er][i] * FAN_TP + a3f[j][i] * FAN_TP_V) * qvA[er][w * 3 + i];
      }
      lgp[j] = a;
      lgp[j] += __shfl_xor(lgp[j], 1);
      lgp[j] += __shfl_xor(lgp[j], 2);
      lgp[j] += __shfl_xor(lgp[j], 4);
      lgp[j] += __shfl_xor(lgp[j], 8);
    }
    if (c == 0) {
#pragma unroll
      for (int j = 0; j < 4; ++j) {
        int er = 32 * wv + 16 * m + 4 * g + j;
        int ee = e0 + er;
        if (ee < E) {
          logit[ee] = lgp[j];
          atomicMaxF(&mx[dstA[er]], lgp[j]);
        }
      }
    }
  }
}

// ---------------- edge kernel 3: V path + scatter ----------------
__global__ void __launch_bounds__(128)
k_edge_v(const float* __restrict__ pos, const float* __restrict__ x,
         const float* __restrict__ fcv1, const unsigned short* __restrict__ wtv,
         const int* __restrict__ srcv, const int* __restrict__ dstv,
         const float* __restrict__ ex, const float* __restrict__ z,
         float* __restrict__ agg, int E) {
  __shared__ alignas(16) unsigned short h_lds[64 * 72];
  __shared__ float fS[48][64];
  __shared__ float y1A[64][4];
  __shared__ float wgtA[64];
  __shared__ int dstA[64];

  const int tid = threadIdx.x;
  const int wv = __builtin_amdgcn_readfirstlane(tid >> 6);
  const int lane = tid & 63;
  const int e0 = blockIdx.x * 64;
  const int eL = e0 + lane;
  const bool valid = eL < E;

  int s = valid ? srcv[eL] : 0, t = valid ? dstv[eL] : 0;

  float y1v[3], d;
  {
    float vx = pos[s * 3 + 0] - pos[t * 3 + 0];
    float vy_ = pos[s * 3 + 1] - pos[t * 3 + 1];
    float vz = pos[s * 3 + 2] - pos[t * 3 + 2];
    d = sqrtf(vx * vx + vy_ * vy_ + vz * vz + 1e-24f);
    float inv = SQ3F / d;
    y1v[0] = vx * inv; y1v[1] = vy_ * inv; y1v[2] = vz * inv;
  }
  float emb[16];
  edge_emb(d, emb);
  {
    float h[32];
    radial_hidden32(fcv1, emb, wv, h);
    pack32(&h_lds[lane * 72 + 32 * wv], h);
  }

  if (wv == 0) {
    const float* xs = x + s * 40;
    float fvl[24];
#pragma unroll
    for (int i = 0; i < 16; ++i) fS[i][lane] = xs[i];
#pragma unroll
    for (int i = 0; i < 24; ++i) { fvl[i] = xs[16 + i]; fS[16 + i][lane] = fvl[i]; }
#pragma unroll
    for (int u = 0; u < 8; ++u)
      fS[40 + u][lane] = (fvl[u * 3] * y1v[0] + fvl[u * 3 + 1] * y1v[1] +
                          fvl[u * 3 + 2] * y1v[2]) * INV_SQ3F;
    y1A[lane][0] = y1v[0]; y1A[lane][1] = y1v[1]; y1A[lane][2] = y1v[2];
    dstA[lane] = t;
    float zz = z[t];
    zz = (zz == 0.f) ? 1.f : zz;
    float alpha = (valid ? ex[eL] : 0.f) / zz;
    wgtA[lane] = sqrtf(alpha + 1e-12f);
  }
  __syncthreads();

  const int c = lane & 15, g = lane >> 4;
  const f32x4 zero4 = {0.f, 0.f, 0.f, 0.f};

  bf16x8 aV[2][2];
#pragma unroll
  for (int m = 0; m < 2; ++m)
#pragma unroll
    for (int ks = 0; ks < 2; ++ks)
      aV[m][ks] = __builtin_bit_cast(
          bf16x8, *(const uint4*)&h_lds[(32 * wv + 16 * m + c) * 72 + 32 * ks + 8 * g]);

  float vs[2][4] = {{0.f}}, b2[2][4] = {{0.f}}, b3[2][4][3] = {{{0.f}}};

#pragma unroll
  for (int T = 0; T < 36; ++T) {
    const unsigned short* bs = wtv + (T * 16 + c) * 64 + 8 * g;
    bf16x8 b0 = __builtin_bit_cast(bf16x8, *(const uint4*)(bs));
    bf16x8 b1 = __builtin_bit_cast(bf16x8, *(const uint4*)(bs + 32));
#pragma unroll
    for (int m = 0; m < 2; ++m) {
      f32x4 acc = __builtin_amdgcn_mfma_f32_16x16x32_bf16(aV[m][0], b0, zero4, 0, 0, 0);
      acc = __builtin_amdgcn_mfma_f32_16x16x32_bf16(aV[m][1], b1, acc, 0, 0, 0);
      const int rb = 32 * wv + 16 * m + 4 * g;
      if (T < 16) {
#pragma unroll
        for (int j = 0; j < 4; ++j) vs[m][j] += fS[T][rb + j] * acc[j];
      } else if (T < 24) {
        int u = 2 * (T - 16) + (c >> 3);
#pragma unroll
        for (int j = 0; j < 4; ++j) b2[m][j] += fS[u][rb + j] * acc[j];
      } else if (T < 28) {
        int u = 2 * (T - 24) + (c >> 3);
#pragma unroll
        for (int j = 0; j < 4; ++j)
#pragma unroll
          for (int i = 0; i < 3; ++i) b3[m][j][i] += fS[16 + u * 3 + i][rb + j] * acc[j];
      } else {
#pragma unroll
        for (int j = 0; j < 4; ++j) vs[m][j] += fS[40 + (T - 28)][rb + j] * acc[j];
      }
    }
  }

#pragma unroll
  for (int m = 0; m < 2; ++m) {
    float b2f[4], b3f[4][3];
#pragma unroll
    for (int j = 0; j < 4; ++j) b2f[j] = b2[m][j] + __shfl_xor(b2[m][j], 8);
#pragma unroll
    for (int j = 0; j < 4; ++j)
#pragma unroll
      for (int i = 0; i < 3; ++i) b3f[j][i] = b3[m][j][i] + __shfl_xor(b3[m][j][i], 8);

    // scatter: lane owns col c of the 4 edges in its (wv, m, g) row block
#pragma unroll
    for (int j = 0; j < 4; ++j) {
      int er = 32 * wv + 16 * m + 4 * g + j;
      int ee = e0 + er;
      if (ee >= E) continue;
      float w = wgtA[er];
      float* at = agg + dstA[er] * 40;
      atomicAdd(&at[c], w * vs[m][j] * FAN_TP);
      if (c < 8) {
#pragma unroll
        for (int i = 0; i < 2; ++i) {
          float v = b2f[j] * y1A[er][i] * FAN_TP + b3f[j][i] * FAN_TP_V;
          atomicAdd(&at[16 + c * 3 + i], w * v);
        }
      } else {
        float v = b2f[j] * y1A[er][2] * FAN_TP + b3f[j][2] * FAN_TP_V;
        atomicAdd(&at[16 + (c - 8) * 3 + 2], w * v);
      }
    }
  }
}

// ---------------- output kernel ----------------
template <bool BF>
__global__ void k_out(const float* __restrict__ x, const float* __restrict__ rb0,
                      const float* __restrict__ rb1, const float* __restrict__ re0,
                      const float* __restrict__ re1, void* __restrict__ out, int N,
                      const int* __restrict__ flag) {
  if ((*flag != 0) != BF) return;
  int n = blockIdx.x * blockDim.x + threadIdx.x;
  if (n >= N) return;
  float b[20], eta[20];
  lin_apply<8, 4>(x + n * 40, rb0, rb1, b);
  lin_apply<8, 4>(x + n * 40, re0, re1, eta);
  if (BF) {
    __hip_bfloat16* o = (__hip_bfloat16*)out;
#pragma unroll
    for (int j = 0; j < 20; ++j) o[n * 20 + j] = __float2bfloat16(b[j]);
#pragma unroll
    for (int j = 0; j < 20; ++j) o[N * 20 + n * 20 + j] = __float2bfloat16(eta[j]);
  } else {
    float* o = (float*)out;
#pragma unroll
    for (int j = 0; j < 20; ++j) o[n * 20 + j] = b[j];
#pragma unroll
    for (int j = 0; j < 20; ++j) o[N * 20 + n * 20 + j] = eta[j];
  }
}

// ---------------- host ----------------
extern "C" void kernel_launch(void* const* d_in, const int* in_sizes, int n_in,
                              void* d_out, int out_size, void* d_ws, size_t ws_size,
                              hipStream_t stream) {
  float* ws = (float*)d_ws;
  const int N = in_sizes[0] / 40;
  const int E = in_sizes[16];
  const int* src = (const int*)d_in[16];
  const int* dst = (const int*)d_in[17];
  int* flag = (int*)(ws + OFF_FLAG);
  unsigned short* wtv = (unsigned short*)(ws + OFF_WT);
  unsigned short* wtk = (unsigned short*)(ws + OFF_WTK);

  k_detect<<<1, 64, 0, stream>>>((const unsigned int*)d_in[0], flag);

  CvtArgs ca;
  const int order[16] = {2, 3, 4, 5, 6, 7, 8, 9, 10, 11, 12, 13, 14, 15, 0, 1};
  const int offs[16] = {OFF_LIN0, OFF_LIN1, OFF_HQ0, OFF_HQ1, OFF_FCK1, OFF_FCK2,
                        OFF_FCV1, OFF_FCV2, OFF_DOT0, OFF_DOT1, OFF_RB0, OFF_RB1,
                        OFF_RE0, OFF_RE1, OFF_F, OFF_POS};
  for (int i = 0; i < 16; ++i) {
    ca.src[i] = d_in[order[i]];
    ca.n[i] = in_sizes[order[i]];
    ca.off[i] = offs[i];
  }
  k_cvt<false><<<512, 256, 0, stream>>>(ca, ws, flag);
  k_cvt<true><<<512, 256, 0, stream>>>(ca, ws, flag);
  k_wt<<<(2 * 576 * 64 + 255) / 256, 256, 0, stream>>>(ws + OFF_FCV2, wtv);
  k_wtk<<<(2 * 288 * 64 + 255) / 256, 256, 0, stream>>>(ws + OFF_FCK2, wtk);

  float* x = ws + OFF_X;
  float* q = ws + OFF_Q;
  float* mx = ws + OFF_MX;
  float* z = ws + OFF_Z;
  float* agg = ws + OFF_AGG;
  float* logit = ws + OFF_LOGIT;
  float* cutb = ws + OFF_CUT;
  float* exb = ws + OFF_EX;
  const float* pos = ws + OFF_POS;

  const int nodeBlocks = (N + 255) / 256;
  const int vecBlocks = (N * 40 + 255) / 256;
  const int edgeBlocks = (E + 255) / 256;
  const int eb64 = (E + 63) / 64;   // block = 64 edges, 128 threads

  k_lin_in<<<nodeBlocks, 256, 0, stream>>>(ws + OFF_F, ws + OFF_LIN0, ws + OFF_LIN1, x, N);

  for (int l = 0; l < 2; ++l) {
    k_init<<<vecBlocks, 256, 0, stream>>>(mx, z, agg, N);
    k_q<<<nodeBlocks, 256, 0, stream>>>(x, ws + OFF_HQ0 + l * 128, ws + OFF_HQ1 + l * 32, q, N);
    k_edge_k<<<eb64, 128, 0, stream>>>(
        pos, x, q, ws + OFF_FCK1 + l * 1024, wtk + l * 18432,
        ws + OFF_DOT0 + l * 64, ws + OFF_DOT1 + l * 16, src, dst, logit, cutb, mx, E);
    k_edge_ex<<<edgeBlocks, 256, 0, stream>>>(dst, logit, cutb, mx, exb, z, E);
    k_edge_v<<<eb64, 128, 0, stream>>>(
        pos, x, ws + OFF_FCV1 + l * 1024, wtv + l * 36864, src, dst, exb, z, agg, E);
    k_update<<<vecBlocks, 256, 0, stream>>>(x, agg, N * 40);
  }

  k_out<false><<<nodeBlocks, 256, 0, stream>>>(x, ws + OFF_RB0, ws + OFF_RB1,
                                               ws + OFF_RE0, ws + OFF_RE1, d_out, N, flag);
  k_out<true><<<nodeBlocks, 256, 0, stream>>>(x, ws + OFF_RB0, ws + OFF_RB1,
                                              ws + OFF_RE0, ws + OFF_RE1, d_out, N, flag);
}

// Round 10
// 287.054 us; speedup vs baseline: 3.6209x; 1.6335x over previous
//
#include <hip/hip_runtime.h>
#include <hip/hip_bf16.h>
#include <math.h>

#define DEV __device__ __forceinline__

typedef __attribute__((ext_vector_type(4))) float f32x4;
typedef __attribute__((ext_vector_type(8))) __bf16 bf16x8;

// ---------------- problem constants ----------------
constexpr int N_CONST = 8192;
constexpr int E_CONST = 131072;

constexpr float SQ3F     = 1.7320508075688772f;
constexpr float INV_SQ3F = 0.57735026918962576f;
constexpr float FAN_TP   = 0.20412414523193150f;   // 24^-0.5
constexpr float FAN_TP_V = 0.35355339059327373f;   // sqrt(3)*24^-0.5
constexpr float FAN_DOT  = 0.11180339887498949f;   // 80^-0.5
constexpr float INV16SQ  = 0.25f;                  // 16^-0.5
constexpr float INV8SQ   = 0.35355339059327373f;   // 8^-0.5
constexpr float HID_SC   = 0.125f;                 // 64^-0.5

// ---------------- workspace layout (float offsets) ----------------
enum : int {
  OFF_LIN0 = 0,
  OFF_LIN1 = OFF_LIN0 + 256,
  OFF_HQ0  = OFF_LIN1 + 64,
  OFF_HQ1  = OFF_HQ0 + 256,
  OFF_FCK1 = OFF_HQ1 + 64,
  OFF_FCK2 = OFF_FCK1 + 2048,
  OFF_FCV1 = OFF_FCK2 + 36864,
  OFF_FCV2 = OFF_FCV1 + 2048,
  OFF_DOT0 = OFF_FCV2 + 73728,
  OFF_DOT1 = OFF_DOT0 + 128,
  OFF_RB0  = OFF_DOT1 + 32,
  OFF_RB1  = OFF_RB0 + 128,
  OFF_RE0  = OFF_RB1 + 32,
  OFF_RE1  = OFF_RE0 + 128,
  OFF_F    = OFF_RE1 + 32,
  OFF_POS  = OFF_F + N_CONST * 40,
  OFF_X    = OFF_POS + N_CONST * 3,
  OFF_Q    = OFF_X + N_CONST * 40,
  OFF_MX   = OFF_Q + N_CONST * 20,
  OFF_Z    = OFF_MX + N_CONST,
  OFF_AGG  = OFF_Z + N_CONST,
  OFF_LOGIT= OFF_AGG + N_CONST * 40,
  OFF_CUT  = OFF_LOGIT + E_CONST,
  OFF_EX   = OFF_CUT + E_CONST,
  OFF_FLAG = OFF_EX + E_CONST,     // int flag in a float slot
  OFF_WT   = (OFF_FLAG + 7) & ~3,  // bf16 WtV [2][36 tiles][1024] (swizzled)
  OFF_WTK  = OFF_WT + 36864,       // bf16 WtK [2][18 tiles][1024] (swizzled)
};

// ---------------- dtype detection ----------------
__global__ void k_detect(const unsigned int* __restrict__ words, int* __restrict__ flag) {
  if (blockIdx.x != 0 || threadIdx.x != 0) return;
  int cnt = 0;
  for (int i = 0; i < 512; ++i) {
    unsigned b = (words[i] >> 8) & 0x7Fu;
    cnt += (b >= 0x3Au && b <= 0x43u) ? 1 : 0;
  }
  *flag = (cnt > 256) ? 1 : 0;
}

// ---------------- convert all float inputs to f32 in ws ----------------
struct CvtArgs {
  const void* src[16];
  int n[16];
  int off[16];
};

template <bool BF>
__global__ void k_cvt(CvtArgs a, float* __restrict__ ws, const int* __restrict__ flag) {
  if ((*flag != 0) != BF) return;
  int tid = blockIdx.x * blockDim.x + threadIdx.x;
  int stride = gridDim.x * blockDim.x;
  for (int arr = 0; arr < 16; ++arr) {
    float* dst = ws + a.off[arr];
    int n = a.n[arr];
    if (BF) {
      const __hip_bfloat16* s = (const __hip_bfloat16*)a.src[arr];
      for (int i = tid; i < n; i += stride) dst[i] = __bfloat162float(s[i]);
    } else {
      const float* s = (const float*)a.src[arr];
      for (int i = tid; i < n; i += stride) dst[i] = s[i];
    }
  }
}

// ---------------- helpers ----------------
DEV unsigned short f2bf(float f) {   // RNE f32 -> bf16 bits
  unsigned int u = __float_as_uint(f);
  u = u + 0x7FFFu + ((u >> 16) & 1u);
  return (unsigned short)(u >> 16);
}

DEV void atomicMaxF(float* addr, float val) {
  unsigned int* ai = (unsigned int*)addr;
  unsigned int old = *ai;
  while (__uint_as_float(old) < val) {
    unsigned int assumed = old;
    old = atomicCAS(ai, assumed, __float_as_uint(val));
    if (old == assumed) break;
  }
}

template <int MO0, int MO1>
DEV void lin_apply(const float* __restrict__ in40, const float* __restrict__ W0,
                   const float* __restrict__ W1, float* __restrict__ out) {
#pragma unroll
  for (int j = 0; j < MO0; ++j) {
    float a = 0.f;
#pragma unroll
    for (int i = 0; i < 16; ++i) a += in40[i] * W0[i * MO0 + j];
    out[j] = a * INV16SQ;
  }
#pragma unroll
  for (int w = 0; w < MO1; ++w) {
    float a0 = 0.f, a1 = 0.f, a2 = 0.f;
#pragma unroll
    for (int u = 0; u < 8; ++u) {
      float wt = W1[u * MO1 + w];
      a0 += in40[16 + u * 3 + 0] * wt;
      a1 += in40[16 + u * 3 + 1] * wt;
      a2 += in40[16 + u * 3 + 2] * wt;
    }
    out[MO0 + w * 3 + 0] = a0 * INV8SQ;
    out[MO0 + w * 3 + 1] = a1 * INV8SQ;
    out[MO0 + w * 3 + 2] = a2 * INV8SQ;
  }
}

DEV void edge_emb(float d, float emb[16]) {
#pragma unroll
  for (int i = 0; i < 16; ++i) {
    float c = (2.0f * (i + 1)) / 17.0f;
    float df = (d - c) * (17.0f * 0.5f);
    emb[i] = __expf(-df * df) * (4.0f / 1.12f);
  }
}

// h for k in [wv*16, wv*16+16); wv wave-uniform
DEV void radial_hidden16(const float* __restrict__ W1, const float emb[16],
                         int wv, float h[16]) {
#pragma unroll 1
  for (int i = 0; i < 16; ++i) {
    float a = 0.f;
#pragma unroll
    for (int j = 0; j < 16; ++j) a += emb[j] * W1[j * 64 + wv * 16 + i];
    a *= INV16SQ;
    float sig = 1.0f / (1.0f + __expf(-a));
    h[i] = a * sig * HID_SC;
  }
}

DEV void pack16(unsigned short* __restrict__ dst, const float h[16]) {
  unsigned int hw[8];
#pragma unroll
  for (int i = 0; i < 8; ++i)
    hw[i] = (unsigned int)f2bf(h[2 * i]) | ((unsigned int)f2bf(h[2 * i + 1]) << 16);
  uint4 w0 = {hw[0], hw[1], hw[2], hw[3]};
  uint4 w1 = {hw[4], hw[5], hw[6], hw[7]};
  *(uint4*)(dst) = w0;
  *(uint4*)(dst + 8) = w1;
}

// B-frag from an LDS-staged, slot-swizzled 2KB weight tile.
// Tile layout (shorts): c*64 + ((k>>3)^(c&7))*8 + (k&7). Read slots s0=g^(c&7)
// (ks=0) and s0^4 (ks=1) recover the original k=32ks+8g+j ordering.
DEV f32x4 gemm2_lds(const unsigned short* __restrict__ wb, int c, int g,
                    bf16x8 a0, bf16x8 a1) {
  const f32x4 zero4 = {0.f, 0.f, 0.f, 0.f};
  int s0 = g ^ (c & 7);
  bf16x8 b0 = __builtin_bit_cast(bf16x8, *(const uint4*)(wb + c * 64 + s0 * 8));
  bf16x8 b1 = __builtin_bit_cast(bf16x8, *(const uint4*)(wb + c * 64 + (s0 ^ 4) * 8));
  f32x4 acc = __builtin_amdgcn_mfma_f32_16x16x32_bf16(a0, b0, zero4, 0, 0, 0);
  return __builtin_amdgcn_mfma_f32_16x16x32_bf16(a1, b1, acc, 0, 0, 0);
}

// ---------------- weight transposes to bf16 (slot-swizzled tiles) ----------------
__global__ void k_wt(const float* __restrict__ fcv2, unsigned short* __restrict__ wt) {
  int tid = blockIdx.x * blockDim.x + threadIdx.x;
  if (tid >= 2 * 36864) return;
  int l = tid / 36864;
  int r = tid - l * 36864;
  int T = r >> 10;
  int w = r & 1023;
  int c = w >> 6;
  int q = w & 63;
  int slot = (q >> 3) ^ (c & 7);
  int k = slot * 8 + (q & 7);
  wt[tid] = f2bf(fcv2[l * 36864 + k * 576 + T * 16 + c]);
}

__global__ void k_wtk(const float* __restrict__ fck2, unsigned short* __restrict__ wtk) {
  int tid = blockIdx.x * blockDim.x + threadIdx.x;
  if (tid >= 2 * 18432) return;
  int l = tid / 18432;
  int r = tid - l * 18432;
  int T = r >> 10;
  int w = r & 1023;
  int c = w >> 6;
  int q = w & 63;
  int slot = (q >> 3) ^ (c & 7);
  int k = slot * 8 + (q & 7);
  wtk[tid] = f2bf(fck2[l * 18432 + k * 288 + T * 16 + c]);
}

// ---------------- node kernels ----------------
__global__ void k_lin_in(const float* __restrict__ f, const float* __restrict__ W0,
                         const float* __restrict__ W1, float* __restrict__ x, int N) {
  int n = blockIdx.x * blockDim.x + threadIdx.x;
  if (n >= N) return;
  lin_apply<16, 8>(f + n * 40, W0, W1, x + n * 40);
}

__global__ void k_q(const float* __restrict__ x, const float* __restrict__ W0,
                    const float* __restrict__ W1, float* __restrict__ q, int N) {
  int n = blockIdx.x * blockDim.x + threadIdx.x;
  if (n >= N) return;
  lin_apply<8, 4>(x + n * 40, W0, W1, q + n * 20);
}

__global__ void k_init(float* __restrict__ mx, float* __restrict__ z,
                       float* __restrict__ agg, int N) {
  int i = blockIdx.x * blockDim.x + threadIdx.x;
  if (i < N * 40) agg[i] = 0.f;
  if (i < N) { mx[i] = -INFINITY; z[i] = 0.f; }
}

__global__ void k_update(float* __restrict__ x, const float* __restrict__ agg, int n) {
  int i = blockIdx.x * blockDim.x + threadIdx.x;
  if (i < n) x[i] += agg[i];
}

// ---------------- edge kernel 2: exp + denominator ----------------
__global__ void k_edge_ex(const int* __restrict__ dstv, const float* __restrict__ logit,
                          const float* __restrict__ cutb, const float* __restrict__ mx,
                          float* __restrict__ ex, float* __restrict__ z, int E) {
  int e = blockIdx.x * blockDim.x + threadIdx.x;
  if (e >= E) return;
  int t = dstv[e];
  float m = mx[t];
  if (m == -INFINITY) m = 0.f;
  float v = cutb[e] * __expf(logit[e] - m);
  ex[e] = v;
  atomicAdd(&z[t], v);
}

// ---------------- edge kernel 1: K path + logits (LDS-staged weights) ----------------
// Round-5 structure: 256 thr = 4 waves, 64 edges, wave wv owns M-tile wv.
// Weights: 18 tiles, 9 phases x 2 tiles, double-buffered via reg-staged async split.
__global__ void __launch_bounds__(256)
k_edge_k(const float* __restrict__ pos, const float* __restrict__ x,
         const float* __restrict__ q,
         const float* __restrict__ fck1, const unsigned short* __restrict__ wtk,
         const float* __restrict__ dot0, const float* __restrict__ dot1,
         const int* __restrict__ srcv, const int* __restrict__ dstv,
         float* __restrict__ logit, float* __restrict__ cutb,
         float* __restrict__ mx, int E) {
  __shared__ alignas(16) unsigned short h_lds[64 * 72];
  __shared__ alignas(16) unsigned short wbuf[2 * 2 * 1024];  // 2 buf x 2 tiles
  __shared__ float fS[48][64];   // fs 0..15 | fv 16..39 | vy 40..47
  __shared__ float y1A[64][4];
  __shared__ float qdA[64][8];
  __shared__ float qvA[64][12];
  __shared__ int dstA[64];

  const int tid = threadIdx.x;
  const int wv = __builtin_amdgcn_readfirstlane(tid >> 6);
  const int lane = tid & 63;
  const int e0 = blockIdx.x * 64;
  const int eL = e0 + lane;
  const bool valid = eL < E;
  const bool ldr = (wv < 2);

  // phase-0 weight preload (tiles 0,1) issued before the long prologue
  uint4 pre0, pre1;
  if (ldr) {
    const unsigned short* gs = wtk + wv * 1024 + lane * 8;
    pre0 = *(const uint4*)(gs);
    pre1 = *(const uint4*)(gs + 512);
  }

  int s = valid ? srcv[eL] : 0, t = valid ? dstv[eL] : 0;

  float y1v[3], d;
  {
    float vx = pos[s * 3 + 0] - pos[t * 3 + 0];
    float vy_ = pos[s * 3 + 1] - pos[t * 3 + 1];
    float vz = pos[s * 3 + 2] - pos[t * 3 + 2];
    d = sqrtf(vx * vx + vy_ * vy_ + vz * vz + 1e-24f);
    float inv = SQ3F / d;
    y1v[0] = vx * inv; y1v[1] = vy_ * inv; y1v[2] = vz * inv;
  }
  float emb[16];
  edge_emb(d, emb);
  {
    float h[16];
    radial_hidden16(fck1, emb, wv, h);
    pack16(&h_lds[lane * 72 + 16 * wv], h);
  }

  if (wv == 0) {
    const float* xs = x + s * 40;
    float fvl[24];
#pragma unroll
    for (int i = 0; i < 16; ++i) fS[i][lane] = xs[i];
#pragma unroll
    for (int i = 0; i < 24; ++i) { fvl[i] = xs[16 + i]; fS[16 + i][lane] = fvl[i]; }
#pragma unroll
    for (int u = 0; u < 8; ++u)
      fS[40 + u][lane] = (fvl[u * 3] * y1v[0] + fvl[u * 3 + 1] * y1v[1] +
                          fvl[u * 3 + 2] * y1v[2]) * INV_SQ3F;
    y1A[lane][0] = y1v[0]; y1A[lane][1] = y1v[1]; y1A[lane][2] = y1v[2];
    dstA[lane] = t;
    if (valid) {
      float uu = 10.0f * (1.0f - 0.5f * d);
      cutb[eL] = (uu > 0.f) ? __expf(-1.0f / fmaxf(uu, 1e-9f)) : 0.f;
    }
    const float* qd_ = q + t * 20;
    float qs_[8], qv_[12];
#pragma unroll
    for (int u = 0; u < 8; ++u) qs_[u] = qd_[u];
#pragma unroll
    for (int i = 0; i < 12; ++i) qv_[i] = qd_[8 + i];
#pragma unroll
    for (int v = 0; v < 8; ++v) {
      float a = 0.f;
#pragma unroll
      for (int u = 0; u < 8; ++u) a += qs_[u] * dot0[u * 8 + v];
      qdA[lane][v] = a * (FAN_DOT * FAN_TP);
    }
#pragma unroll
    for (int v = 0; v < 4; ++v)
#pragma unroll
      for (int i = 0; i < 3; ++i) {
        float a = 0.f;
#pragma unroll
        for (int u = 0; u < 4; ++u) a += qv_[u * 3 + i] * dot1[u * 4 + v];
        qvA[lane][v * 3 + i] = a * (FAN_DOT * INV_SQ3F);
      }
  }
  if (ldr) {
    unsigned short* wd = wbuf + wv * 1024 + lane * 8;
    *(uint4*)(wd) = pre0;
    *(uint4*)(wd + 512) = pre1;
  }
  __syncthreads();

  const int c = lane & 15, g = lane >> 4;
  const int erow = 16 * wv + 4 * g;

  bf16x8 a0 = __builtin_bit_cast(bf16x8, *(const uint4*)&h_lds[(16 * wv + c) * 72 + 8 * g]);
  bf16x8 a1 = __builtin_bit_cast(bf16x8, *(const uint4*)&h_lds[(16 * wv + c) * 72 + 32 + 8 * g]);

  float ksp[4] = {0.f, 0.f, 0.f, 0.f};
  float a2p[4] = {0.f, 0.f, 0.f, 0.f};
  float a3p[4][3] = {{0.f}};

#pragma unroll 1
  for (int p = 0; p < 9; ++p) {
    uint4 nb0, nb1;
    const bool hasNext = (p < 8) && ldr;
    if (hasNext) {
      const unsigned short* gs = wtk + (2 * (p + 1) + wv) * 1024 + lane * 8;
      nb0 = *(const uint4*)(gs);
      nb1 = *(const uint4*)(gs + 512);
    }
    const unsigned short* wb = wbuf + (p & 1) * 2048;
#pragma unroll
    for (int t2 = 0; t2 < 2; ++t2) {
      int T = 2 * p + t2;
      f32x4 acc = gemm2_lds(wb + t2 * 1024, c, g, a0, a1);
      if (T < 8) {
        int u = 2 * T + (c >> 3);
#pragma unroll
        for (int j = 0; j < 4; ++j) ksp[j] += fS[u][erow + j] * acc[j];
      } else if (T < 12) {
        int u = 4 * (T - 8) + (c >> 2);
#pragma unroll
        for (int j = 0; j < 4; ++j) a2p[j] += fS[u][erow + j] * acc[j];
      } else if (T < 14) {
        int u = 4 * (T - 12) + (c >> 2);
#pragma unroll
        for (int j = 0; j < 4; ++j)
#pragma unroll
          for (int i = 0; i < 3; ++i) a3p[j][i] += fS[16 + u * 3 + i][erow + j] * acc[j];
      } else {
        int u = 2 * (T - 14) + (c >> 3);
#pragma unroll
        for (int j = 0; j < 4; ++j) ksp[j] += fS[40 + u][erow + j] * acc[j];
      }
    }
    if (hasNext) {
      unsigned short* wd = wbuf + ((p + 1) & 1) * 2048 + wv * 1024 + lane * 8;
      *(uint4*)(wd) = nb0;
      *(uint4*)(wd + 512) = nb1;
    }
    __syncthreads();
  }

  float ksf[4], a2f[4], a3f[4][3];
#pragma unroll
  for (int j = 0; j < 4; ++j) ksf[j] = ksp[j] + __shfl_xor(ksp[j], 8);
#pragma unroll
  for (int j = 0; j < 4; ++j) {
    float v = a2p[j] + __shfl_xor(a2p[j], 4);
    a2f[j] = v + __shfl_xor(v, 8);
  }
#pragma unroll
  for (int j = 0; j < 4; ++j)
#pragma unroll
    for (int i = 0; i < 3; ++i) {
      float v = a3p[j][i] + __shfl_xor(a3p[j][i], 4);
      a3f[j][i] = v + __shfl_xor(v, 8);
    }

  float lgp[4];
#pragma unroll
  for (int j = 0; j < 4; ++j) {
    float a = 0.f;
    int er = erow + j;
    if (c < 8) {
      a = ksf[j] * qdA[er][c];
    } else if (c < 12) {
      int w = c - 8;
#pragma unroll
      for (int i = 0; i < 3; ++i)
        a += (a2f[j] * y1A[er][i] * FAN_TP + a3f[j][i] * FAN_TP_V) * qvA[er][w * 3 + i];
    }
    lgp[j] = a;
  }
#pragma unroll
  for (int j = 0; j < 4; ++j) {
    lgp[j] += __shfl_xor(lgp[j], 1);
    lgp[j] += __shfl_xor(lgp[j], 2);
    lgp[j] += __shfl_xor(lgp[j], 4);
    lgp[j] += __shfl_xor(lgp[j], 8);
  }
  if (c == 0) {
#pragma unroll
    for (int j = 0; j < 4; ++j) {
      int ee = e0 + erow + j;
      if (ee < E) {
        logit[ee] = lgp[j];
        atomicMaxF(&mx[dstA[erow + j]], lgp[j]);
      }
    }
  }
}

// ---------------- edge kernel 3: V path + scatter (LDS-staged weights) ----------------
// 36 tiles, 9 phases x 4 tiles, double-buffered.
__global__ void __launch_bounds__(256)
k_edge_v(const float* __restrict__ pos, const float* __restrict__ x,
         const float* __restrict__ fcv1, const unsigned short* __restrict__ wtv,
         const int* __restrict__ srcv, const int* __restrict__ dstv,
         const float* __restrict__ ex, const float* __restrict__ z,
         float* __restrict__ agg, int E) {
  __shared__ alignas(16) unsigned short h_lds[64 * 72];
  __shared__ alignas(16) unsigned short wbuf[2 * 4 * 1024];  // 2 buf x 4 tiles
  __shared__ float fS[48][64];
  __shared__ float y1A[64][4];
  __shared__ float wgtA[64];
  __shared__ int dstA[64];

  const int tid = threadIdx.x;
  const int wv = __builtin_amdgcn_readfirstlane(tid >> 6);
  const int lane = tid & 63;
  const int e0 = blockIdx.x * 64;
  const int eL = e0 + lane;
  const bool valid = eL < E;

  // phase-0 weight preload (tiles 0..3)
  uint4 pre0, pre1;
  {
    const unsigned short* gs = wtv + wv * 1024 + lane * 8;
    pre0 = *(const uint4*)(gs);
    pre1 = *(const uint4*)(gs + 512);
  }

  int s = valid ? srcv[eL] : 0, t = valid ? dstv[eL] : 0;

  float y1v[3], d;
  {
    float vx = pos[s * 3 + 0] - pos[t * 3 + 0];
    float vy_ = pos[s * 3 + 1] - pos[t * 3 + 1];
    float vz = pos[s * 3 + 2] - pos[t * 3 + 2];
    d = sqrtf(vx * vx + vy_ * vy_ + vz * vz + 1e-24f);
    float inv = SQ3F / d;
    y1v[0] = vx * inv; y1v[1] = vy_ * inv; y1v[2] = vz * inv;
  }
  float emb[16];
  edge_emb(d, emb);
  {
    float h[16];
    radial_hidden16(fcv1, emb, wv, h);
    pack16(&h_lds[lane * 72 + 16 * wv], h);
  }

  if (wv == 0) {
    const float* xs = x + s * 40;
    float fvl[24];
#pragma unroll
    for (int i = 0; i < 16; ++i) fS[i][lane] = xs[i];
#pragma unroll
    for (int i = 0; i < 24; ++i) { fvl[i] = xs[16 + i]; fS[16 + i][lane] = fvl[i]; }
#pragma unroll
    for (int u = 0; u < 8; ++u)
      fS[40 + u][lane] = (fvl[u * 3] * y1v[0] + fvl[u * 3 + 1] * y1v[1] +
                          fvl[u * 3 + 2] * y1v[2]) * INV_SQ3F;
    y1A[lane][0] = y1v[0]; y1A[lane][1] = y1v[1]; y1A[lane][2] = y1v[2];
    dstA[lane] = t;
    float zz = z[t];
    zz = (zz == 0.f) ? 1.f : zz;
    float alpha = (valid ? ex[eL] : 0.f) / zz;
    wgtA[lane] = sqrtf(alpha + 1e-12f);
  }
  {
    unsigned short* wd = wbuf + wv * 1024 + lane * 8;
    *(uint4*)(wd) = pre0;
    *(uint4*)(wd + 512) = pre1;
  }
  __syncthreads();

  const int c = lane & 15, g = lane >> 4;
  const int erow = 16 * wv + 4 * g;

  bf16x8 a0 = __builtin_bit_cast(bf16x8, *(const uint4*)&h_lds[(16 * wv + c) * 72 + 8 * g]);
  bf16x8 a1 = __builtin_bit_cast(bf16x8, *(const uint4*)&h_lds[(16 * wv + c) * 72 + 32 + 8 * g]);

  float vs[4] = {0.f, 0.f, 0.f, 0.f};
  float b2[4] = {0.f, 0.f, 0.f, 0.f};
  float b3[4][3] = {{0.f}};

#pragma unroll 1
  for (int p = 0; p < 9; ++p) {
    uint4 nb0, nb1;
    const bool hasNext = (p < 8);
    if (hasNext) {
      const unsigned short* gs = wtv + (4 * (p + 1) + wv) * 1024 + lane * 8;
      nb0 = *(const uint4*)(gs);
      nb1 = *(const uint4*)(gs + 512);
    }
    const unsigned short* wb = wbuf + (p & 1) * 4096;
#pragma unroll
    for (int t2 = 0; t2 < 4; ++t2) {
      int T = 4 * p + t2;
      f32x4 acc = gemm2_lds(wb + t2 * 1024, c, g, a0, a1);
      if (T < 16) {
#pragma unroll
        for (int j = 0; j < 4; ++j) vs[j] += fS[T][erow + j] * acc[j];
      } else if (T < 24) {
        int u = 2 * (T - 16) + (c >> 3);
#pragma unroll
        for (int j = 0; j < 4; ++j) b2[j] += fS[u][erow + j] * acc[j];
      } else if (T < 28) {
        int u = 2 * (T - 24) + (c >> 3);
#pragma unroll
        for (int j = 0; j < 4; ++j)
#pragma unroll
          for (int i = 0; i < 3; ++i) b3[j][i] += fS[16 + u * 3 + i][erow + j] * acc[j];
      } else {
#pragma unroll
        for (int j = 0; j < 4; ++j) vs[j] += fS[40 + (T - 28)][erow + j] * acc[j];
      }
    }
    if (hasNext) {
      unsigned short* wd = wbuf + ((p + 1) & 1) * 4096 + wv * 1024 + lane * 8;
      *(uint4*)(wd) = nb0;
      *(uint4*)(wd + 512) = nb1;
    }
    __syncthreads();
  }

#pragma unroll
  for (int j = 0; j < 4; ++j) b2[j] += __shfl_xor(b2[j], 8);
#pragma unroll
  for (int j = 0; j < 4; ++j)
#pragma unroll
    for (int i = 0; i < 3; ++i) b3[j][i] += __shfl_xor(b3[j][i], 8);

  // scatter: lane owns col c of 4 edges
#pragma unroll
  for (int j = 0; j < 4; ++j) {
    int er = erow + j;
    int ee = e0 + er;
    if (ee >= E) continue;
    float w = wgtA[er];
    float* at = agg + dstA[er] * 40;
    atomicAdd(&at[c], w * vs[j] * FAN_TP);
    if (c < 8) {
#pragma unroll
      for (int i = 0; i < 2; ++i) {
        float v = b2[j] * y1A[er][i] * FAN_TP + b3[j][i] * FAN_TP_V;
        atomicAdd(&at[16 + c * 3 + i], w * v);
      }
    } else {
      float v = b2[j] * y1A[er][2] * FAN_TP + b3[j][2] * FAN_TP_V;
      atomicAdd(&at[16 + (c - 8) * 3 + 2], w * v);
    }
  }
}

// ---------------- output kernel ----------------
template <bool BF>
__global__ void k_out(const float* __restrict__ x, const float* __restrict__ rb0,
                      const float* __restrict__ rb1, const float* __restrict__ re0,
                      const float* __restrict__ re1, void* __restrict__ out, int N,
                      const int* __restrict__ flag) {
  if ((*flag != 0) != BF) return;
  int n = blockIdx.x * blockDim.x + threadIdx.x;
  if (n >= N) return;
  float b[20], eta[20];
  lin_apply<8, 4>(x + n * 40, rb0, rb1, b);
  lin_apply<8, 4>(x + n * 40, re0, re1, eta);
  if (BF) {
    __hip_bfloat16* o = (__hip_bfloat16*)out;
#pragma unroll
    for (int j = 0; j < 20; ++j) o[n * 20 + j] = __float2bfloat16(b[j]);
#pragma unroll
    for (int j = 0; j < 20; ++j) o[N * 20 + n * 20 + j] = __float2bfloat16(eta[j]);
  } else {
    float* o = (float*)out;
#pragma unroll
    for (int j = 0; j < 20; ++j) o[n * 20 + j] = b[j];
#pragma unroll
    for (int j = 0; j < 20; ++j) o[N * 20 + n * 20 + j] = eta[j];
  }
}

// ---------------- host ----------------
extern "C" void kernel_launch(void* const* d_in, const int* in_sizes, int n_in,
                              void* d_out, int out_size, void* d_ws, size_t ws_size,
                              hipStream_t stream) {
  float* ws = (float*)d_ws;
  const int N = in_sizes[0] / 40;
  const int E = in_sizes[16];
  const int* src = (const int*)d_in[16];
  const int* dst = (const int*)d_in[17];
  int* flag = (int*)(ws + OFF_FLAG);
  unsigned short* wtv = (unsigned short*)(ws + OFF_WT);
  unsigned short* wtk = (unsigned short*)(ws + OFF_WTK);

  k_detect<<<1, 64, 0, stream>>>((const unsigned int*)d_in[0], flag);

  CvtArgs ca;
  const int order[16] = {2, 3, 4, 5, 6, 7, 8, 9, 10, 11, 12, 13, 14, 15, 0, 1};
  const int offs[16] = {OFF_LIN0, OFF_LIN1, OFF_HQ0, OFF_HQ1, OFF_FCK1, OFF_FCK2,
                        OFF_FCV1, OFF_FCV2, OFF_DOT0, OFF_DOT1, OFF_RB0, OFF_RB1,
                        OFF_RE0, OFF_RE1, OFF_F, OFF_POS};
  for (int i = 0; i < 16; ++i) {
    ca.src[i] = d_in[order[i]];
    ca.n[i] = in_sizes[order[i]];
    ca.off[i] = offs[i];
  }
  k_cvt<false><<<512, 256, 0, stream>>>(ca, ws, flag);
  k_cvt<true><<<512, 256, 0, stream>>>(ca, ws, flag);
  k_wt<<<(2 * 36864 + 255) / 256, 256, 0, stream>>>(ws + OFF_FCV2, wtv);
  k_wtk<<<(2 * 18432 + 255) / 256, 256, 0, stream>>>(ws + OFF_FCK2, wtk);

  float* x = ws + OFF_X;
  float* q = ws + OFF_Q;
  float* mx = ws + OFF_MX;
  float* z = ws + OFF_Z;
  float* agg = ws + OFF_AGG;
  float* logit = ws + OFF_LOGIT;
  float* cutb = ws + OFF_CUT;
  float* exb = ws + OFF_EX;
  const float* pos = ws + OFF_POS;

  const int nodeBlocks = (N + 255) / 256;
  const int vecBlocks = (N * 40 + 255) / 256;
  const int edgeBlocks = (E + 255) / 256;
  const int eb64 = (E + 63) / 64;   // block = 64 edges, 256 threads

  k_lin_in<<<nodeBlocks, 256, 0, stream>>>(ws + OFF_F, ws + OFF_LIN0, ws + OFF_LIN1, x, N);

  for (int l = 0; l < 2; ++l) {
    k_init<<<vecBlocks, 256, 0, stream>>>(mx, z, agg, N);
    k_q<<<nodeBlocks, 256, 0, stream>>>(x, ws + OFF_HQ0 + l * 128, ws + OFF_HQ1 + l * 32, q, N);
    k_edge_k<<<eb64, 256, 0, stream>>>(
        pos, x, q, ws + OFF_FCK1 + l * 1024, wtk + l * 18432,
        ws + OFF_DOT0 + l * 64, ws + OFF_DOT1 + l * 16, src, dst, logit, cutb, mx, E);
    k_edge_ex<<<edgeBlocks, 256, 0, stream>>>(dst, logit, cutb, mx, exb, z, E);
    k_edge_v<<<eb64, 256, 0, stream>>>(
        pos, x, ws + OFF_FCV1 + l * 1024, wtv + l * 36864, src, dst, exb, z, agg, E);
    k_update<<<vecBlocks, 256, 0, stream>>>(x, agg, N * 40);
  }

  k_out<false><<<nodeBlocks, 256, 0, stream>>>(x, ws + OFF_RB0, ws + OFF_RB1,
                                               ws + OFF_RE0, ws + OFF_RE1, d_out, N, flag);
  k_out<true><<<nodeBlocks, 256, 0, stream>>>(x, ws + OFF_RB0, ws + OFF_RB1,
                                              ws + OFF_RE0, ws + OFF_RE1, d_out, N, flag);
}